// Round 1
// baseline (251.577 us; speedup 1.0000x reference)
//
#include <hip/hip_runtime.h>
#include <hip/hip_bf16.h>

typedef __bf16 bf16x8 __attribute__((ext_vector_type(8)));
typedef float  f32x4  __attribute__((ext_vector_type(4)));

#define MFMA16(a,b,c) __builtin_amdgcn_mfma_f32_16x16x32_bf16(a,b,c,0,0,0)

constexpr int   Bc = 4, Sc = 2048, Hc = 16, Dc = 64;
constexpr int   HD  = Hc * Dc;        // 1024
constexpr int   SHD = Sc * HD;
constexpr float SCALE = 0.125f;       // 1/sqrt(64)
constexpr float LOG2E = 1.4426950408889634f;
constexpr float NEG   = -1e30f;

__global__ __launch_bounds__(256, 2) void fattn_kernel(
    const float* __restrict__ Q, const float* __restrict__ K,
    const float* __restrict__ V, const int* __restrict__ VL,
    float* __restrict__ O)
{
    __shared__ __bf16 Vt[64 * 64];        // V^T tile: [d][key], swizzled
    __shared__ __bf16 Pl[4][32 * 64];     // per-wave P: [qrow32][key], swizzled

    const int bid  = blockIdx.x;
    const int qt   = bid & 15;            // 16 q-tiles of 128 rows
    const int h    = (bid >> 4) & 15;
    const int b    = bid >> 8;
    const int tid  = threadIdx.x;
    const int wid  = tid >> 6;
    const int lane = tid & 63;
    const int li   = lane & 15;
    const int lg   = lane >> 4;
    const int vl   = VL[b];

    const size_t base = (size_t)b * SHD + (size_t)h * Dc;

    // ---- Q fragments (pre-scaled), A-layout: row=li, k=lg*8+j (+32*ks) ----
    bf16x8 aq[2][2];
    const int qrow0 = qt * 128 + wid * 32;
    #pragma unroll
    for (int m = 0; m < 2; ++m) {
        const float* qp = Q + base + (size_t)(qrow0 + m * 16 + li) * HD + lg * 8;
        #pragma unroll
        for (int ks = 0; ks < 2; ++ks) {
            float4 x0 = *(const float4*)(qp + ks * 32);
            float4 x1 = *(const float4*)(qp + ks * 32 + 4);
            bf16x8 f;
            f[0] = (__bf16)(x0.x * SCALE); f[1] = (__bf16)(x0.y * SCALE);
            f[2] = (__bf16)(x0.z * SCALE); f[3] = (__bf16)(x0.w * SCALE);
            f[4] = (__bf16)(x1.x * SCALE); f[5] = (__bf16)(x1.y * SCALE);
            f[6] = (__bf16)(x1.z * SCALE); f[7] = (__bf16)(x1.w * SCALE);
            aq[m][ks] = f;
        }
    }

    bf16x8 bones;
    #pragma unroll
    for (int j = 0; j < 8; ++j) bones[j] = (__bf16)1.0f;

    f32x4 acc[2][4];
    float mst[2][4], lst[2][4];
    #pragma unroll
    for (int m = 0; m < 2; ++m) {
        #pragma unroll
        for (int r = 0; r < 4; ++r) { mst[m][r] = NEG; lst[m][r] = 0.f; }
        #pragma unroll
        for (int dt = 0; dt < 4; ++dt) {
            #pragma unroll
            for (int r = 0; r < 4; ++r) acc[m][dt][r] = 0.f;
        }
    }

    const int ntiles = (vl + 63) >> 6;
    const int sd  = tid & 63;             // staging: this thread's d
    const int skb = (tid >> 6) * 8;       // staging: key base
    const float* vpd = V + base + sd;

    for (int t = 0; t < ntiles; ++t) {
        const int kv0 = t * 64;

        // ---- stage V^T into LDS (coalesced scalar loads, swizzled b128 writes)
        __syncthreads();                  // all waves done reading old Vt
        #pragma unroll
        for (int rep = 0; rep < 2; ++rep) {
            const int kb = skb + rep * 32;
            bf16x8 pk;
            #pragma unroll
            for (int j = 0; j < 8; ++j)
                pk[j] = (__bf16)vpd[(size_t)(kv0 + kb + j) * HD];
            const int el = (sd * 64 + kb) ^ ((sd & 7) << 3);
            *(bf16x8*)&Vt[el] = pk;
        }
        __syncthreads();

        // ---- QK^T: K B-fragments straight from global (L1/L2 resident) ----
        f32x4 s[2][4];
        #pragma unroll
        for (int m = 0; m < 2; ++m)
            #pragma unroll
            for (int nt = 0; nt < 4; ++nt)
                #pragma unroll
                for (int r = 0; r < 4; ++r) s[m][nt][r] = 0.f;

        #pragma unroll
        for (int nt = 0; nt < 4; ++nt) {
            const float* kp = K + base + (size_t)(kv0 + nt * 16 + li) * HD + lg * 8;
            #pragma unroll
            for (int ks = 0; ks < 2; ++ks) {
                float4 x0 = *(const float4*)(kp + ks * 32);
                float4 x1 = *(const float4*)(kp + ks * 32 + 4);
                bf16x8 f;
                f[0] = (__bf16)x0.x; f[1] = (__bf16)x0.y;
                f[2] = (__bf16)x0.z; f[3] = (__bf16)x0.w;
                f[4] = (__bf16)x1.x; f[5] = (__bf16)x1.y;
                f[6] = (__bf16)x1.z; f[7] = (__bf16)x1.w;
                #pragma unroll
                for (int m = 0; m < 2; ++m)
                    s[m][nt] = MFMA16(aq[m][ks], f, s[m][nt]);
            }
        }

        // ---- key mask: key = kv0 + nt*16 + li (col = li in D-layout) ----
        bool kva[4];
        #pragma unroll
        for (int nt = 0; nt < 4; ++nt) kva[nt] = (kv0 + nt * 16 + li) < vl;
        #pragma unroll
        for (int m = 0; m < 2; ++m)
            #pragma unroll
            for (int nt = 0; nt < 4; ++nt)
                #pragma unroll
                for (int r = 0; r < 4; ++r)
                    if (!kva[nt]) s[m][nt][r] = NEG;

        // ---- online softmax; D-layout row = lg*4 + r ----
        #pragma unroll
        for (int m = 0; m < 2; ++m) {
            #pragma unroll
            for (int r = 0; r < 4; ++r) {
                float tm = fmaxf(fmaxf(s[m][0][r], s[m][1][r]),
                                 fmaxf(s[m][2][r], s[m][3][r]));
                tm = fmaxf(tm, __shfl_xor(tm, 1));
                tm = fmaxf(tm, __shfl_xor(tm, 2));
                tm = fmaxf(tm, __shfl_xor(tm, 4));
                tm = fmaxf(tm, __shfl_xor(tm, 8));
                const float mn  = fmaxf(mst[m][r], tm);
                const float fac = exp2f((mst[m][r] - mn) * LOG2E);
                mst[m][r] = mn;
                lst[m][r] *= fac;
                #pragma unroll
                for (int dt = 0; dt < 4; ++dt) acc[m][dt][r] *= fac;
                const int qr  = m * 16 + lg * 4 + r;
                const int swz = (qr & 7) << 3;
                #pragma unroll
                for (int nt = 0; nt < 4; ++nt) {
                    float p = exp2f((s[m][nt][r] - mn) * LOG2E);
                    Pl[wid][(qr * 64 + nt * 16 + li) ^ swz] = (__bf16)p;
                }
            }
        }

        // ---- P A-fragments back from LDS (wave-local, no barrier needed) ----
        bf16x8 ap[2][2];
        #pragma unroll
        for (int m = 0; m < 2; ++m) {
            const int qr  = m * 16 + li;
            const int swz = (qr & 7) << 3;
            #pragma unroll
            for (int ks = 0; ks < 2; ++ks)
                ap[m][ks] = *(bf16x8*)&Pl[wid][(qr * 64 + ks * 32 + lg * 8) ^ swz];
        }

        // ---- row sums via ones-MFMA (replaces 32 cross-lane adds) ----
        #pragma unroll
        for (int m = 0; m < 2; ++m) {
            f32x4 rs;
            #pragma unroll
            for (int r = 0; r < 4; ++r) rs[r] = 0.f;
            rs = MFMA16(ap[m][0], bones, rs);
            rs = MFMA16(ap[m][1], bones, rs);
            #pragma unroll
            for (int r = 0; r < 4; ++r) lst[m][r] += rs[r];
        }

        // ---- PV: V B-fragments from swizzled Vt (conflict-free b128) ----
        #pragma unroll
        for (int dt = 0; dt < 4; ++dt) {
            const int d   = dt * 16 + li;
            const int swz = (d & 7) << 3;
            #pragma unroll
            for (int ks = 0; ks < 2; ++ks) {
                bf16x8 bv = *(bf16x8*)&Vt[(d * 64 + ks * 32 + lg * 8) ^ swz];
                #pragma unroll
                for (int m = 0; m < 2; ++m)
                    acc[m][dt] = MFMA16(ap[m][ks], bv, acc[m][dt]);
            }
        }
    }

    // ---- epilogue: O = acc / l ----
    #pragma unroll
    for (int m = 0; m < 2; ++m) {
        #pragma unroll
        for (int r = 0; r < 4; ++r) {
            const float inv = 1.0f / lst[m][r];
            float* op = O + base + (size_t)(qrow0 + m * 16 + lg * 4 + r) * HD;
            #pragma unroll
            for (int dt = 0; dt < 4; ++dt)
                op[dt * 16 + li] = acc[m][dt][r] * inv;
        }
    }
}

extern "C" void kernel_launch(void* const* d_in, const int* in_sizes, int n_in,
                              void* d_out, int out_size, void* d_ws, size_t ws_size,
                              hipStream_t stream) {
    (void)in_sizes; (void)n_in; (void)out_size; (void)d_ws; (void)ws_size;
    const float* q    = (const float*)d_in[0];
    const float* k    = (const float*)d_in[1];
    const float* v    = (const float*)d_in[2];
    const int*   vlen = (const int*)d_in[3];
    float*       out  = (float*)d_out;
    dim3 grid(Bc * Hc * (Sc / 128));   // 1024 blocks: [b][h][qtile]
    fattn_kernel<<<grid, 256, 0, stream>>>(q, k, v, vlen, out);
}

// Round 2
// 226.871 us; speedup vs baseline: 1.1089x; 1.1089x over previous
//
#include <hip/hip_runtime.h>
#include <hip/hip_bf16.h>

typedef __bf16 bf16x8 __attribute__((ext_vector_type(8)));
typedef float  f32x4  __attribute__((ext_vector_type(4)));

#define MFMA16(a,b,c) __builtin_amdgcn_mfma_f32_16x16x32_bf16(a,b,c,0,0,0)

constexpr int   Bc = 4, Sc = 2048, Hc = 16, Dc = 64;
constexpr int   HD  = Hc * Dc;        // 1024
constexpr int   SHD = Sc * HD;
constexpr float SCALE = 0.125f;       // 1/sqrt(64)
constexpr float LOG2E = 1.4426950408889634f;
constexpr float QSC   = SCALE * LOG2E; // fold log2e into Q -> pure exp2 later
constexpr float NEG   = -1e30f;
constexpr size_t KV_ELEMS = (size_t)Bc * Hc * Sc * Dc;   // 8388608 per tensor

// ---------------- prepass: K,V [b][s][h][d] f32 -> [b][h][s][d] bf16 -------
__global__ __launch_bounds__(256) void cvt_kernel(
    const float* __restrict__ K, const float* __restrict__ V,
    __bf16* __restrict__ Kb, __bf16* __restrict__ Vb)
{
    const int o  = blockIdx.x * 256 + threadIdx.x;  // 16-elem chunk, out order
    const int d0 = (o & 3) * 16;
    const int ro = o >> 2;                 // out row = (b*16+h)*2048 + s
    const int s  = ro & 2047;
    const int h  = (ro >> 11) & 15;
    const int b  = ro >> 15;
    const size_t iof = (size_t)((b * 2048 + s) * 16 + h) * 64 + d0;
    const size_t oof = (size_t)ro * 64 + d0;

    #pragma unroll
    for (int which = 0; which < 2; ++which) {
        const float* src = (which == 0) ? (K + iof) : (V + iof);
        __bf16*      dst = (which == 0) ? (Kb + oof) : (Vb + oof);
        bf16x8 lo, hi;
        #pragma unroll
        for (int q = 0; q < 2; ++q) {
            float4 a = *(const float4*)(src + q * 8);
            float4 c = *(const float4*)(src + q * 8 + 4);
            lo[q*4+0] = (__bf16)a.x; lo[q*4+1] = (__bf16)a.y;
            lo[q*4+2] = (__bf16)a.z; lo[q*4+3] = (__bf16)a.w;
            hi[q*4+0] = (__bf16)c.x; hi[q*4+1] = (__bf16)c.y;
            hi[q*4+2] = (__bf16)c.z; hi[q*4+3] = (__bf16)c.w;
        }
        // interleave back to memory order: elems 0..7 = a0..a3,c0..c3 pattern
        bf16x8 w0, w1;
        w0[0]=lo[0]; w0[1]=lo[1]; w0[2]=lo[2]; w0[3]=lo[3];
        w0[4]=hi[0]; w0[5]=hi[1]; w0[6]=hi[2]; w0[7]=hi[3];
        w1[0]=lo[4]; w1[1]=lo[5]; w1[2]=lo[6]; w1[3]=lo[7];
        w1[4]=hi[4]; w1[5]=hi[5]; w1[6]=hi[6]; w1[7]=hi[7];
        *(bf16x8*)(dst)     = w0;
        *(bf16x8*)(dst + 8) = w1;
    }
}

// ---------------- main attention kernel (bf16 K/V from workspace) ----------
template<bool MASK>
__device__ __forceinline__ void kv_tile(
    int kv0, int vl,
    const __bf16* __restrict__ kb, const __bf16* __restrict__ vpd,
    __bf16* Vt, __bf16* Plw,
    const bf16x8 aq[2][2], const bf16x8& bones,
    f32x4 acc[2][4], float mst[2][4], float lst[2][4],
    int li, int lg, int tid)
{
    // ---- stage V^T tile into swizzled LDS (bf16 source, coalesced rows) ----
    __syncthreads();
    const int sd  = tid & 63;
    const int skb = (tid >> 6) * 8;
    #pragma unroll
    for (int rep = 0; rep < 2; ++rep) {
        const int kbv = skb + rep * 32;
        bf16x8 pk;
        #pragma unroll
        for (int j = 0; j < 8; ++j) pk[j] = vpd[(size_t)(kv0 + kbv + j) * 64];
        const int el = (sd * 64 + kbv) ^ ((sd & 7) << 3);
        *(bf16x8*)&Vt[el] = pk;
    }
    __syncthreads();

    // ---- QK^T: direct bf16x8 K fragments from global ----
    f32x4 s[2][4];
    #pragma unroll
    for (int m = 0; m < 2; ++m)
        #pragma unroll
        for (int nt = 0; nt < 4; ++nt)
            #pragma unroll
            for (int r = 0; r < 4; ++r) s[m][nt][r] = 0.f;

    #pragma unroll
    for (int nt = 0; nt < 4; ++nt) {
        const __bf16* kp = kb + (size_t)(kv0 + nt * 16 + li) * 64 + lg * 8;
        #pragma unroll
        for (int ks = 0; ks < 2; ++ks) {
            bf16x8 f = *(const bf16x8*)(kp + ks * 32);
            #pragma unroll
            for (int m = 0; m < 2; ++m)
                s[m][nt] = MFMA16(aq[m][ks], f, s[m][nt]);
        }
    }

    if (MASK) {
        bool kva[4];
        #pragma unroll
        for (int nt = 0; nt < 4; ++nt) kva[nt] = (kv0 + nt * 16 + li) < vl;
        #pragma unroll
        for (int m = 0; m < 2; ++m)
            #pragma unroll
            for (int nt = 0; nt < 4; ++nt)
                #pragma unroll
                for (int r = 0; r < 4; ++r)
                    if (!kva[nt]) s[m][nt][r] = NEG;
    }

    // ---- online softmax (log2 domain; rescale only when max grows) ----
    #pragma unroll
    for (int m = 0; m < 2; ++m) {
        #pragma unroll
        for (int r = 0; r < 4; ++r) {
            float tm = fmaxf(fmaxf(s[m][0][r], s[m][1][r]),
                             fmaxf(s[m][2][r], s[m][3][r]));
            tm = fmaxf(tm, __shfl_xor(tm, 1));
            tm = fmaxf(tm, __shfl_xor(tm, 2));
            tm = fmaxf(tm, __shfl_xor(tm, 4));
            tm = fmaxf(tm, __shfl_xor(tm, 8));
            float mn = mst[m][r];
            if (__any(tm > mn)) {                 // exact: skipped => fac==1
                mn = fmaxf(mn, tm);
                const float fac = __builtin_amdgcn_exp2f(mst[m][r] - mn);
                lst[m][r] *= fac;
                #pragma unroll
                for (int dt = 0; dt < 4; ++dt) acc[m][dt][r] *= fac;
                mst[m][r] = mn;
            }
            const int qr  = m * 16 + lg * 4 + r;
            const int swz = (qr & 7) << 3;
            #pragma unroll
            for (int nt = 0; nt < 4; ++nt) {
                float p = __builtin_amdgcn_exp2f(s[m][nt][r] - mn);
                Plw[(qr * 64 + nt * 16 + li) ^ swz] = (__bf16)p;
            }
        }
    }

    // ---- P A-fragments back from wave-local LDS ----
    bf16x8 ap[2][2];
    #pragma unroll
    for (int m = 0; m < 2; ++m) {
        const int qr  = m * 16 + li;
        const int swz = (qr & 7) << 3;
        #pragma unroll
        for (int ks = 0; ks < 2; ++ks)
            ap[m][ks] = *(bf16x8*)&Plw[(qr * 64 + ks * 32 + lg * 8) ^ swz];
    }

    // ---- row sums via ones-MFMA ----
    #pragma unroll
    for (int m = 0; m < 2; ++m) {
        f32x4 rs;
        #pragma unroll
        for (int r = 0; r < 4; ++r) rs[r] = 0.f;
        rs = MFMA16(ap[m][0], bones, rs);
        rs = MFMA16(ap[m][1], bones, rs);
        #pragma unroll
        for (int r = 0; r < 4; ++r) lst[m][r] += rs[r];
    }

    // ---- PV from swizzled Vt ----
    #pragma unroll
    for (int dt = 0; dt < 4; ++dt) {
        const int d   = dt * 16 + li;
        const int swz = (d & 7) << 3;
        #pragma unroll
        for (int ks = 0; ks < 2; ++ks) {
            bf16x8 bv = *(bf16x8*)&Vt[(d * 64 + ks * 32 + lg * 8) ^ swz];
            #pragma unroll
            for (int m = 0; m < 2; ++m)
                acc[m][dt] = MFMA16(ap[m][ks], bv, acc[m][dt]);
        }
    }
}

__global__ __launch_bounds__(256, 2) void fattn_kernel(
    const float* __restrict__ Q, const __bf16* __restrict__ Kb,
    const __bf16* __restrict__ Vb, const int* __restrict__ VL,
    float* __restrict__ O)
{
    __shared__ __bf16 Vt[64 * 64];
    __shared__ __bf16 Pl[4][32 * 64];

    const int bid  = blockIdx.x;
    const int qt   = bid & 15;
    const int h    = (bid >> 4) & 15;
    const int b    = bid >> 8;
    const int tid  = threadIdx.x;
    const int wid  = tid >> 6;
    const int lane = tid & 63;
    const int li   = lane & 15;
    const int lg   = lane >> 4;
    const int vl   = VL[b];

    const size_t qbase = (size_t)b * SHD + (size_t)h * Dc;           // fp32 [b][s][h][d]
    const size_t hb    = ((size_t)b * Hc + h) * Sc * Dc;             // bf16 [b][h][s][d]
    const __bf16* kb  = Kb + hb;
    const __bf16* vpd = Vb + hb + (tid & 63);

    // ---- Q fragments, pre-scaled by SCALE*LOG2E ----
    bf16x8 aq[2][2];
    const int qrow0 = qt * 128 + wid * 32;
    #pragma unroll
    for (int m = 0; m < 2; ++m) {
        const float* qp = Q + qbase + (size_t)(qrow0 + m * 16 + li) * HD + lg * 8;
        #pragma unroll
        for (int ks = 0; ks < 2; ++ks) {
            float4 x0 = *(const float4*)(qp + ks * 32);
            float4 x1 = *(const float4*)(qp + ks * 32 + 4);
            bf16x8 f;
            f[0] = (__bf16)(x0.x * QSC); f[1] = (__bf16)(x0.y * QSC);
            f[2] = (__bf16)(x0.z * QSC); f[3] = (__bf16)(x0.w * QSC);
            f[4] = (__bf16)(x1.x * QSC); f[5] = (__bf16)(x1.y * QSC);
            f[6] = (__bf16)(x1.z * QSC); f[7] = (__bf16)(x1.w * QSC);
            aq[m][ks] = f;
        }
    }

    bf16x8 bones;
    #pragma unroll
    for (int j = 0; j < 8; ++j) bones[j] = (__bf16)1.0f;

    f32x4 acc[2][4];
    float mst[2][4], lst[2][4];
    #pragma unroll
    for (int m = 0; m < 2; ++m) {
        #pragma unroll
        for (int r = 0; r < 4; ++r) { mst[m][r] = NEG; lst[m][r] = 0.f; }
        #pragma unroll
        for (int dt = 0; dt < 4; ++dt)
            #pragma unroll
            for (int r = 0; r < 4; ++r) acc[m][dt][r] = 0.f;
    }

    const int nfull = vl >> 6;
    const int tail  = vl & 63;
    for (int t = 0; t < nfull; ++t)
        kv_tile<false>(t * 64, vl, kb, vpd, Vt, Pl[wid], aq, bones,
                       acc, mst, lst, li, lg, tid);
    if (tail)
        kv_tile<true>(nfull * 64, vl, kb, vpd, Vt, Pl[wid], aq, bones,
                      acc, mst, lst, li, lg, tid);

    #pragma unroll
    for (int m = 0; m < 2; ++m) {
        #pragma unroll
        for (int r = 0; r < 4; ++r) {
            const float inv = 1.0f / lst[m][r];
            float* op = O + qbase + (size_t)(qrow0 + m * 16 + lg * 4 + r) * HD;
            #pragma unroll
            for (int dt = 0; dt < 4; ++dt)
                op[dt * 16 + li] = acc[m][dt][r] * inv;
        }
    }
}

// ---------------- fallback (round-1 kernel, fp32 K/V, no workspace) --------
__global__ __launch_bounds__(256, 2) void fattn_fb(
    const float* __restrict__ Q, const float* __restrict__ K,
    const float* __restrict__ V, const int* __restrict__ VL,
    float* __restrict__ O)
{
    __shared__ __bf16 Vt[64 * 64];
    __shared__ __bf16 Pl[4][32 * 64];
    const int bid = blockIdx.x;
    const int qt = bid & 15, h = (bid >> 4) & 15, b = bid >> 8;
    const int tid = threadIdx.x, wid = tid >> 6, lane = tid & 63;
    const int li = lane & 15, lg = lane >> 4;
    const int vl = VL[b];
    const size_t base = (size_t)b * SHD + (size_t)h * Dc;
    bf16x8 aq[2][2];
    const int qrow0 = qt * 128 + wid * 32;
    #pragma unroll
    for (int m = 0; m < 2; ++m) {
        const float* qp = Q + base + (size_t)(qrow0 + m * 16 + li) * HD + lg * 8;
        #pragma unroll
        for (int ks = 0; ks < 2; ++ks) {
            float4 x0 = *(const float4*)(qp + ks * 32);
            float4 x1 = *(const float4*)(qp + ks * 32 + 4);
            bf16x8 f;
            f[0]=(__bf16)(x0.x*QSC); f[1]=(__bf16)(x0.y*QSC);
            f[2]=(__bf16)(x0.z*QSC); f[3]=(__bf16)(x0.w*QSC);
            f[4]=(__bf16)(x1.x*QSC); f[5]=(__bf16)(x1.y*QSC);
            f[6]=(__bf16)(x1.z*QSC); f[7]=(__bf16)(x1.w*QSC);
            aq[m][ks] = f;
        }
    }
    bf16x8 bones;
    #pragma unroll
    for (int j = 0; j < 8; ++j) bones[j] = (__bf16)1.0f;
    f32x4 acc[2][4]; float mst[2][4], lst[2][4];
    #pragma unroll
    for (int m = 0; m < 2; ++m) {
        #pragma unroll
        for (int r = 0; r < 4; ++r) { mst[m][r] = NEG; lst[m][r] = 0.f; }
        #pragma unroll
        for (int dt = 0; dt < 4; ++dt)
            #pragma unroll
            for (int r = 0; r < 4; ++r) acc[m][dt][r] = 0.f;
    }
    const int ntiles = (vl + 63) >> 6;
    const int sd = tid & 63, skb = (tid >> 6) * 8;
    const float* vpd = V + base + sd;
    for (int t = 0; t < ntiles; ++t) {
        const int kv0 = t * 64;
        __syncthreads();
        #pragma unroll
        for (int rep = 0; rep < 2; ++rep) {
            const int kb2 = skb + rep * 32;
            bf16x8 pk;
            #pragma unroll
            for (int j = 0; j < 8; ++j) pk[j] = (__bf16)vpd[(size_t)(kv0+kb2+j)*HD];
            *(bf16x8*)&Vt[(sd*64+kb2) ^ ((sd&7)<<3)] = pk;
        }
        __syncthreads();
        f32x4 s[2][4];
        #pragma unroll
        for (int m = 0; m < 2; ++m)
            #pragma unroll
            for (int nt = 0; nt < 4; ++nt)
                #pragma unroll
                for (int r = 0; r < 4; ++r) s[m][nt][r] = 0.f;
        #pragma unroll
        for (int nt = 0; nt < 4; ++nt) {
            const float* kp = K + base + (size_t)(kv0+nt*16+li)*HD + lg*8;
            #pragma unroll
            for (int ks = 0; ks < 2; ++ks) {
                float4 x0 = *(const float4*)(kp + ks*32);
                float4 x1 = *(const float4*)(kp + ks*32 + 4);
                bf16x8 f;
                f[0]=(__bf16)x0.x; f[1]=(__bf16)x0.y; f[2]=(__bf16)x0.z; f[3]=(__bf16)x0.w;
                f[4]=(__bf16)x1.x; f[5]=(__bf16)x1.y; f[6]=(__bf16)x1.z; f[7]=(__bf16)x1.w;
                #pragma unroll
                for (int m = 0; m < 2; ++m) s[m][nt] = MFMA16(aq[m][ks], f, s[m][nt]);
            }
        }
        bool kva[4];
        #pragma unroll
        for (int nt = 0; nt < 4; ++nt) kva[nt] = (kv0 + nt*16 + li) < vl;
        #pragma unroll
        for (int m = 0; m < 2; ++m)
            #pragma unroll
            for (int nt = 0; nt < 4; ++nt)
                #pragma unroll
                for (int r = 0; r < 4; ++r)
                    if (!kva[nt]) s[m][nt][r] = NEG;
        #pragma unroll
        for (int m = 0; m < 2; ++m) {
            #pragma unroll
            for (int r = 0; r < 4; ++r) {
                float tm = fmaxf(fmaxf(s[m][0][r], s[m][1][r]),
                                 fmaxf(s[m][2][r], s[m][3][r]));
                tm = fmaxf(tm, __shfl_xor(tm, 1));
                tm = fmaxf(tm, __shfl_xor(tm, 2));
                tm = fmaxf(tm, __shfl_xor(tm, 4));
                tm = fmaxf(tm, __shfl_xor(tm, 8));
                const float mn = fmaxf(mst[m][r], tm);
                const float fac = __builtin_amdgcn_exp2f(mst[m][r] - mn);
                mst[m][r] = mn; lst[m][r] *= fac;
                #pragma unroll
                for (int dt = 0; dt < 4; ++dt) acc[m][dt][r] *= fac;
                const int qr = m*16 + lg*4 + r, swz = (qr & 7) << 3;
                #pragma unroll
                for (int nt = 0; nt < 4; ++nt)
                    Pl[wid][(qr*64 + nt*16 + li) ^ swz] =
                        (__bf16)__builtin_amdgcn_exp2f(s[m][nt][r] - mn);
            }
        }
        bf16x8 ap[2][2];
        #pragma unroll
        for (int m = 0; m < 2; ++m) {
            const int qr = m*16 + li, swz = (qr & 7) << 3;
            #pragma unroll
            for (int ks = 0; ks < 2; ++ks)
                ap[m][ks] = *(bf16x8*)&Pl[wid][(qr*64 + ks*32 + lg*8) ^ swz];
        }
        #pragma unroll
        for (int m = 0; m < 2; ++m) {
            f32x4 rs;
            #pragma unroll
            for (int r = 0; r < 4; ++r) rs[r] = 0.f;
            rs = MFMA16(ap[m][0], bones, rs);
            rs = MFMA16(ap[m][1], bones, rs);
            #pragma unroll
            for (int r = 0; r < 4; ++r) lst[m][r] += rs[r];
        }
        #pragma unroll
        for (int dt = 0; dt < 4; ++dt) {
            const int d = dt*16 + li, swz = (d & 7) << 3;
            #pragma unroll
            for (int ks = 0; ks < 2; ++ks) {
                bf16x8 bv = *(bf16x8*)&Vt[(d*64 + ks*32 + lg*8) ^ swz];
                #pragma unroll
                for (int m = 0; m < 2; ++m)
                    acc[m][dt] = MFMA16(ap[m][ks], bv, acc[m][dt]);
            }
        }
    }
    #pragma unroll
    for (int m = 0; m < 2; ++m) {
        #pragma unroll
        for (int r = 0; r < 4; ++r) {
            const float inv = 1.0f / lst[m][r];
            float* op = O + base + (size_t)(qrow0 + m*16 + lg*4 + r) * HD;
            #pragma unroll
            for (int dt = 0; dt < 4; ++dt) op[dt*16 + li] = acc[m][dt][r] * inv;
        }
    }
}

extern "C" void kernel_launch(void* const* d_in, const int* in_sizes, int n_in,
                              void* d_out, int out_size, void* d_ws, size_t ws_size,
                              hipStream_t stream) {
    (void)in_sizes; (void)n_in; (void)out_size;
    const float* q    = (const float*)d_in[0];
    const float* k    = (const float*)d_in[1];
    const float* v    = (const float*)d_in[2];
    const int*   vlen = (const int*)d_in[3];
    float*       out  = (float*)d_out;
    const size_t need = 2 * KV_ELEMS * sizeof(__bf16);   // 33.5 MB
    if (ws_size >= need) {
        __bf16* kb = (__bf16*)d_ws;
        __bf16* vb = kb + KV_ELEMS;
        cvt_kernel<<<dim3(2048), 256, 0, stream>>>(k, v, kb, vb);
        fattn_kernel<<<dim3(Bc * Hc * (Sc / 128)), 256, 0, stream>>>(q, kb, vb, vlen, out);
    } else {
        fattn_fb<<<dim3(Bc * Hc * (Sc / 128)), 256, 0, stream>>>(q, k, v, vlen, out);
    }
}

// Round 4
// 198.622 us; speedup vs baseline: 1.2666x; 1.1422x over previous
//
#include <hip/hip_runtime.h>
#include <hip/hip_bf16.h>

typedef __bf16 bf16x8 __attribute__((ext_vector_type(8)));
typedef float  f32x4  __attribute__((ext_vector_type(4)));
typedef float  f32x16 __attribute__((ext_vector_type(16)));
typedef unsigned int u32;
typedef u32 u32x4 __attribute__((ext_vector_type(4)));

#define MFMA16(a,b,c) __builtin_amdgcn_mfma_f32_16x16x32_bf16(a,b,c,0,0,0)
#define MFMA32(a,b,c) __builtin_amdgcn_mfma_f32_32x32x16_bf16(a,b,c,0,0,0)

constexpr int   Bc = 4, Sc = 2048, Hc = 16, Dc = 64;
constexpr int   HD  = Hc * Dc;        // 1024
constexpr int   SHD = Sc * HD;
constexpr float SCALE = 0.125f;       // 1/sqrt(64)
constexpr float LOG2E = 1.4426950408889634f;
constexpr float QSC   = SCALE * LOG2E;
constexpr float NEG   = -1e30f;
constexpr size_t KV_ELEMS = (size_t)Bc * Hc * Sc * Dc;   // 8388608 per tensor

// ---------------- prepass: K,V [b][s][h][d] f32 -> [b][h][s][d] bf16 -------
__global__ __launch_bounds__(256) void cvt_kernel(
    const float* __restrict__ K, const float* __restrict__ V,
    __bf16* __restrict__ Kb, __bf16* __restrict__ Vb)
{
    const int o  = blockIdx.x * 256 + threadIdx.x;  // 16-elem chunk, out order
    const int d0 = (o & 3) * 16;
    const int ro = o >> 2;
    const int s  = ro & 2047;
    const int h  = (ro >> 11) & 15;
    const int b  = ro >> 15;
    const size_t iof = (size_t)((b * 2048 + s) * 16 + h) * 64 + d0;
    const size_t oof = (size_t)ro * 64 + d0;

    #pragma unroll
    for (int which = 0; which < 2; ++which) {
        const float* src = (which == 0) ? (K + iof) : (V + iof);
        __bf16*      dst = (which == 0) ? (Kb + oof) : (Vb + oof);
        #pragma unroll
        for (int q = 0; q < 2; ++q) {
            float4 a = *(const float4*)(src + q * 8);
            float4 c = *(const float4*)(src + q * 8 + 4);
            bf16x8 w;
            w[0]=(__bf16)a.x; w[1]=(__bf16)a.y; w[2]=(__bf16)a.z; w[3]=(__bf16)a.w;
            w[4]=(__bf16)c.x; w[5]=(__bf16)c.y; w[6]=(__bf16)c.z; w[7]=(__bf16)c.w;
            *(bf16x8*)(dst + q * 8) = w;
        }
    }
}

// ---------------- main: swapped QK^T AND swapped PV, in-register softmax ---
// QK^T: D[row=key][col=q=l31]  (A=K-frag, B=Q-frag)
// PV  : D[row=d]  [col=q=l31]  (A=V^T-frag, B=P-frag)  -> per-lane state
//       (m, lsum, acc) all belong to q = lane&31; rescale is lane-local.
__global__ __launch_bounds__(256, 2) void fattn2(
    const float* __restrict__ Q, const __bf16* __restrict__ Kb,
    const __bf16* __restrict__ Vb, const int* __restrict__ VL,
    float* __restrict__ O)
{
    __shared__ __bf16 Vt[2][64 * 64];   // V^T double buffer: [d][key], swizzled

    const int bid  = blockIdx.x;
    const int b    = bid & 3;           // interleave batches for load balance
    const int h    = (bid >> 2) & 15;
    const int qt   = bid >> 6;
    const int tid  = threadIdx.x;
    const int wid  = tid >> 6;
    const int lane = tid & 63;
    const int l31  = lane & 31;
    const int hi   = lane >> 5;
    const int vl   = VL[b];

    const size_t qbase = (size_t)b * SHD + (size_t)h * Dc;      // fp32 [b][s][h][d]
    const size_t hb    = ((size_t)b * Hc + h) * (size_t)(Sc * Dc);
    const __bf16* kb = Kb + hb;
    const __bf16* vb = Vb + hb;

    // ---- Q B-fragments: col q = qrow0+l31, k: d = dk*16 + hi*8 + j --------
    const int qrow0 = qt * 128 + wid * 32;
    bf16x8 qf[4];
    {
        const float* qp = Q + qbase + (size_t)(qrow0 + l31) * HD + hi * 8;
        #pragma unroll
        for (int dk = 0; dk < 4; ++dk) {
            float4 x0 = *(const float4*)(qp + dk * 16);
            float4 x1 = *(const float4*)(qp + dk * 16 + 4);
            bf16x8 f;
            f[0]=(__bf16)(x0.x*QSC); f[1]=(__bf16)(x0.y*QSC);
            f[2]=(__bf16)(x0.z*QSC); f[3]=(__bf16)(x0.w*QSC);
            f[4]=(__bf16)(x1.x*QSC); f[5]=(__bf16)(x1.y*QSC);
            f[6]=(__bf16)(x1.z*QSC); f[7]=(__bf16)(x1.w*QSC);
            qf[dk] = f;
        }
    }

    f32x16 acc[2];
    #pragma unroll
    for (int i = 0; i < 16; ++i) { acc[0][i] = 0.f; acc[1][i] = 0.f; }
    float m = NEG, lsum = 0.f;

    const int nt   = (vl + 63) >> 6;
    const int ntm1 = nt - 1;
    const bool hastail = (vl & 63) != 0;

    // staging roles (256 threads): d = tid&63, keys wid*8 + rep*32 + j
    const int sd  = tid & 63;
    const int skb = wid * 8;
    const int swr = (sd & 7) << 3;

    // ---- prologue: V(0) -> buf0; prefetch V(1), K(0) ----
    bf16x8 vr[2];
    #pragma unroll
    for (int rep = 0; rep < 2; ++rep)
        #pragma unroll
        for (int j = 0; j < 8; ++j)
            vr[rep][j] = vb[(size_t)(skb + rep * 32 + j) * 64 + sd];
    #pragma unroll
    for (int rep = 0; rep < 2; ++rep)
        *(bf16x8*)&Vt[0][(sd * 64 + skb + rep * 32) ^ swr] = vr[rep];
    {
        const int t1 = (1 <= ntm1) ? 1 : ntm1;
        #pragma unroll
        for (int rep = 0; rep < 2; ++rep)
            #pragma unroll
            for (int j = 0; j < 8; ++j)
                vr[rep][j] = vb[(size_t)(t1 * 64 + skb + rep * 32 + j) * 64 + sd];
    }
    bf16x8 kf[2][4];
    #pragma unroll
    for (int g = 0; g < 2; ++g)
        #pragma unroll
        for (int dk = 0; dk < 4; ++dk)
            kf[g][dk] = *(const bf16x8*)(kb + (size_t)(32 * g + l31) * 64 + dk * 16 + hi * 8);

    for (int t = 0; t < nt; ++t) {
        const int kv0 = t * 64;
        __syncthreads();   // prev-iter PV done everywhere; staged writes visible

        // ---- QK^T swapped: s D-layout col=q(l31), row=key=cr(i,hi) --------
        f32x16 s[2];
        #pragma unroll
        for (int i = 0; i < 16; ++i) { s[0][i] = 0.f; s[1][i] = 0.f; }
        #pragma unroll
        for (int g = 0; g < 2; ++g)
            #pragma unroll
            for (int dk = 0; dk < 4; ++dk)
                s[g] = MFMA32(kf[g][dk], qf[dk], s[g]);

        // ---- prefetch K(t+1) ----
        {
            const int tn = (t < ntm1) ? t + 1 : ntm1;
            #pragma unroll
            for (int g = 0; g < 2; ++g)
                #pragma unroll
                for (int dk = 0; dk < 4; ++dk)
                    kf[g][dk] = *(const bf16x8*)(kb + (size_t)(tn * 64 + 32 * g + l31) * 64 + dk * 16 + hi * 8);
        }

        // ---- stage V(t+1) into buf[(t+1)&1]; prefetch V(t+2) ----
        if (t < ntm1) {
            #pragma unroll
            for (int rep = 0; rep < 2; ++rep)
                *(bf16x8*)&Vt[(t + 1) & 1][(sd * 64 + skb + rep * 32) ^ swr] = vr[rep];
            const int t2 = (t + 2 <= ntm1) ? t + 2 : ntm1;
            #pragma unroll
            for (int rep = 0; rep < 2; ++rep)
                #pragma unroll
                for (int j = 0; j < 8; ++j)
                    vr[rep][j] = vb[(size_t)(t2 * 64 + skb + rep * 32 + j) * 64 + sd];
        }

        // ---- tail mask: key = kv0 + 32g + (i&3) + 8*(i>>2) + 4*hi --------
        if (t == ntm1 && hastail) {
            #pragma unroll
            for (int g = 0; g < 2; ++g)
                #pragma unroll
                for (int i = 0; i < 16; ++i) {
                    const int key = kv0 + 32 * g + (i & 3) + 8 * (i >> 2) + 4 * hi;
                    if (key >= vl) s[g][i] = NEG;
                }
        }

        // ---- in-register online softmax (q = l31; all state lane-local) --
        float tm = fmaxf(s[0][0], s[1][0]);
        #pragma unroll
        for (int i = 1; i < 16; ++i) tm = fmaxf(tm, fmaxf(s[0][i], s[1][i]));
        tm = fmaxf(tm, __shfl_xor(tm, 32));      // other key-half, same q
        if (__any(tm > m)) {
            const float mn  = fmaxf(m, tm);
            const float fac = __builtin_amdgcn_exp2f(m - mn);
            lsum *= fac;
            #pragma unroll
            for (int i = 0; i < 16; ++i) { acc[0][i] *= fac; acc[1][i] *= fac; }
            m = mn;
        }
        #pragma unroll
        for (int g = 0; g < 2; ++g)
            #pragma unroll
            for (int i = 0; i < 16; ++i) {
                const float p = __builtin_amdgcn_exp2f(s[g][i] - m);
                s[g][i] = p;
                lsum += p;
            }

        // ---- pack P -> bf16, redistribute so lane holds P[q=l31][key-slice]
        bf16x8 ap[4];
        #pragma unroll
        for (int g = 0; g < 2; ++g) {
            u32 w[8];
            #pragma unroll
            for (int qd = 0; qd < 4; ++qd) {
                asm("v_cvt_pk_bf16_f32 %0, %1, %2"
                    : "=v"(w[2*qd])   : "v"(s[g][4*qd]),   "v"(s[g][4*qd+1]));
                asm("v_cvt_pk_bf16_f32 %0, %1, %2"
                    : "=v"(w[2*qd+1]) : "v"(s[g][4*qd+2]), "v"(s[g][4*qd+3]));
            }
            #pragma unroll
            for (int tt = 0; tt < 2; ++tt) {
                const u32 sx0 = (u32)__shfl_xor((int)w[4*tt+0], 32);
                const u32 sx1 = (u32)__shfl_xor((int)w[4*tt+1], 32);
                const u32 sx2 = (u32)__shfl_xor((int)w[4*tt+2], 32);
                const u32 sx3 = (u32)__shfl_xor((int)w[4*tt+3], 32);
                u32x4 fw;
                fw.x = hi ? sx2 : w[4*tt+0];
                fw.y = hi ? sx3 : w[4*tt+1];
                fw.z = hi ? w[4*tt+2] : sx0;
                fw.w = hi ? w[4*tt+3] : sx1;
                ap[2*g + tt] = __builtin_bit_cast(bf16x8, fw);
            }
        }

        // ---- PV swapped: A = V^T frag (rows d), B = P frag (cols q) ------
        const __bf16* vtc = Vt[t & 1];
        #pragma unroll
        for (int dt = 0; dt < 2; ++dt) {
            const int d    = dt * 32 + l31;
            const int rowb = d * 64;
            const int swz  = (d & 7) << 3;
            #pragma unroll
            for (int kt = 0; kt < 4; ++kt) {
                bf16x8 bv = *(const bf16x8*)&vtc[(rowb + kt * 16 + hi * 8) ^ swz];
                acc[dt] = MFMA32(bv, ap[kt], acc[dt]);   // D[row=d][col=q]
            }
        }
    }

    // ---- epilogue: all acc regs belong to q = l31; lane-local normalize --
    const float lfull = lsum + __shfl_xor(lsum, 32);
    const float linv  = 1.0f / lfull;
    float* op = O + qbase + (size_t)(qrow0 + l31) * HD;
    #pragma unroll
    for (int dt = 0; dt < 2; ++dt) {
        #pragma unroll
        for (int qd = 0; qd < 4; ++qd) {
            // reg r = 4*qd + rr  ->  d = dt*32 + qd*8 + 4*hi + rr
            float4 wv;
            wv.x = acc[dt][4*qd+0] * linv;
            wv.y = acc[dt][4*qd+1] * linv;
            wv.z = acc[dt][4*qd+2] * linv;
            wv.w = acc[dt][4*qd+3] * linv;
            *(float4*)(op + dt * 32 + qd * 8 + 4 * hi) = wv;
        }
    }
}

// ---------------- fallback (fp32 K/V, no workspace) ------------------------
__global__ __launch_bounds__(256, 2) void fattn_fb(
    const float* __restrict__ Q, const float* __restrict__ K,
    const float* __restrict__ V, const int* __restrict__ VL,
    float* __restrict__ O)
{
    __shared__ __bf16 Vts[64 * 64];
    __shared__ __bf16 Pl[4][32 * 64];
    const int bid = blockIdx.x;
    const int qt = bid & 15, h = (bid >> 4) & 15, b = bid >> 8;
    const int tid = threadIdx.x, wid = tid >> 6, lane = tid & 63;
    const int li = lane & 15, lg = lane >> 4;
    const int vl = VL[b];
    const size_t base = (size_t)b * SHD + (size_t)h * Dc;
    bf16x8 aq[2][2];
    const int qrow0 = qt * 128 + wid * 32;
    #pragma unroll
    for (int m = 0; m < 2; ++m) {
        const float* qp = Q + base + (size_t)(qrow0 + m * 16 + li) * HD + lg * 8;
        #pragma unroll
        for (int ks = 0; ks < 2; ++ks) {
            float4 x0 = *(const float4*)(qp + ks * 32);
            float4 x1 = *(const float4*)(qp + ks * 32 + 4);
            bf16x8 f;
            f[0]=(__bf16)(x0.x*QSC); f[1]=(__bf16)(x0.y*QSC);
            f[2]=(__bf16)(x0.z*QSC); f[3]=(__bf16)(x0.w*QSC);
            f[4]=(__bf16)(x1.x*QSC); f[5]=(__bf16)(x1.y*QSC);
            f[6]=(__bf16)(x1.z*QSC); f[7]=(__bf16)(x1.w*QSC);
            aq[m][ks] = f;
        }
    }
    bf16x8 bones;
    #pragma unroll
    for (int j = 0; j < 8; ++j) bones[j] = (__bf16)1.0f;
    f32x4 acc[2][4]; float mst[2][4], lst[2][4];
    #pragma unroll
    for (int m = 0; m < 2; ++m) {
        #pragma unroll
        for (int r = 0; r < 4; ++r) { mst[m][r] = NEG; lst[m][r] = 0.f; }
        #pragma unroll
        for (int dt = 0; dt < 4; ++dt)
            #pragma unroll
            for (int r = 0; r < 4; ++r) acc[m][dt][r] = 0.f;
    }
    const int ntiles = (vl + 63) >> 6;
    const int sd = tid & 63, skb = (tid >> 6) * 8;
    const float* vpd = V + base + sd;
    for (int t = 0; t < ntiles; ++t) {
        const int kv0 = t * 64;
        __syncthreads();
        #pragma unroll
        for (int rep = 0; rep < 2; ++rep) {
            const int kb2 = skb + rep * 32;
            bf16x8 pk;
            #pragma unroll
            for (int j = 0; j < 8; ++j) pk[j] = (__bf16)vpd[(size_t)(kv0+kb2+j)*HD];
            *(bf16x8*)&Vts[(sd*64+kb2) ^ ((sd&7)<<3)] = pk;
        }
        __syncthreads();
        f32x4 s[2][4];
        #pragma unroll
        for (int m = 0; m < 2; ++m)
            #pragma unroll
            for (int nt = 0; nt < 4; ++nt)
                #pragma unroll
                for (int r = 0; r < 4; ++r) s[m][nt][r] = 0.f;
        #pragma unroll
        for (int nt = 0; nt < 4; ++nt) {
            const float* kp = K + base + (size_t)(kv0+nt*16+li)*HD + lg*8;
            #pragma unroll
            for (int ks = 0; ks < 2; ++ks) {
                float4 x0 = *(const float4*)(kp + ks*32);
                float4 x1 = *(const float4*)(kp + ks*32 + 4);
                bf16x8 f;
                f[0]=(__bf16)x0.x; f[1]=(__bf16)x0.y; f[2]=(__bf16)x0.z; f[3]=(__bf16)x0.w;
                f[4]=(__bf16)x1.x; f[5]=(__bf16)x1.y; f[6]=(__bf16)x1.z; f[7]=(__bf16)x1.w;
                #pragma unroll
                for (int m = 0; m < 2; ++m) s[m][nt] = MFMA16(aq[m][ks], f, s[m][nt]);
            }
        }
        bool kva[4];
        #pragma unroll
        for (int nt = 0; nt < 4; ++nt) kva[nt] = (kv0 + nt*16 + li) < vl;
        #pragma unroll
        for (int m = 0; m < 2; ++m)
            #pragma unroll
            for (int nt = 0; nt < 4; ++nt)
                #pragma unroll
                for (int r = 0; r < 4; ++r)
                    if (!kva[nt]) s[m][nt][r] = NEG;
        #pragma unroll
        for (int m = 0; m < 2; ++m) {
            #pragma unroll
            for (int r = 0; r < 4; ++r) {
                float tm = fmaxf(fmaxf(s[m][0][r], s[m][1][r]),
                                 fmaxf(s[m][2][r], s[m][3][r]));
                tm = fmaxf(tm, __shfl_xor(tm, 1));
                tm = fmaxf(tm, __shfl_xor(tm, 2));
                tm = fmaxf(tm, __shfl_xor(tm, 4));
                tm = fmaxf(tm, __shfl_xor(tm, 8));
                const float mn = fmaxf(mst[m][r], tm);
                const float fac = __builtin_amdgcn_exp2f(mst[m][r] - mn);
                mst[m][r] = mn; lst[m][r] *= fac;
                #pragma unroll
                for (int dt = 0; dt < 4; ++dt) acc[m][dt][r] *= fac;
                const int qr = m*16 + lg*4 + r, swz = (qr & 7) << 3;
                #pragma unroll
                for (int nt = 0; nt < 4; ++nt)
                    Pl[wid][(qr*64 + nt*16 + li) ^ swz] =
                        (__bf16)__builtin_amdgcn_exp2f(s[m][nt][r] - mn);
            }
        }
        bf16x8 ap[2][2];
        #pragma unroll
        for (int m = 0; m < 2; ++m) {
            const int qr = m*16 + li, swz = (qr & 7) << 3;
            #pragma unroll
            for (int ks = 0; ks < 2; ++ks)
                ap[m][ks] = *(bf16x8*)&Pl[wid][(qr*64 + ks*32 + lg*8) ^ swz];
        }
        #pragma unroll
        for (int m = 0; m < 2; ++m) {
            f32x4 rs;
            #pragma unroll
            for (int r = 0; r < 4; ++r) rs[r] = 0.f;
            rs = MFMA16(ap[m][0], bones, rs);
            rs = MFMA16(ap[m][1], bones, rs);
            #pragma unroll
            for (int r = 0; r < 4; ++r) lst[m][r] += rs[r];
        }
        #pragma unroll
        for (int dt = 0; dt < 4; ++dt) {
            const int d = dt*16 + li, swz = (d & 7) << 3;
            #pragma unroll
            for (int ks = 0; ks < 2; ++ks) {
                bf16x8 bv = *(bf16x8*)&Vts[(d*64 + ks*32 + lg*8) ^ swz];
                #pragma unroll
                for (int m = 0; m < 2; ++m)
                    acc[m][dt] = MFMA16(ap[m][ks], bv, acc[m][dt]);
            }
        }
    }
    #pragma unroll
    for (int m = 0; m < 2; ++m) {
        #pragma unroll
        for (int r = 0; r < 4; ++r) {
            const float inv = 1.0f / lst[m][r];
            float* op = O + base + (size_t)(qrow0 + m*16 + lg*4 + r) * HD;
            #pragma unroll
            for (int dt = 0; dt < 4; ++dt) op[dt*16 + li] = acc[m][dt][r] * inv;
        }
    }
}

extern "C" void kernel_launch(void* const* d_in, const int* in_sizes, int n_in,
                              void* d_out, int out_size, void* d_ws, size_t ws_size,
                              hipStream_t stream) {
    (void)in_sizes; (void)n_in; (void)out_size;
    const float* q    = (const float*)d_in[0];
    const float* k    = (const float*)d_in[1];
    const float* v    = (const float*)d_in[2];
    const int*   vlen = (const int*)d_in[3];
    float*       out  = (float*)d_out;
    const size_t need = 2 * KV_ELEMS * sizeof(__bf16);   // 33.5 MB
    if (ws_size >= need) {
        __bf16* kbp = (__bf16*)d_ws;
        __bf16* vbp = kbp + KV_ELEMS;
        cvt_kernel<<<dim3(2048), 256, 0, stream>>>(k, v, kbp, vbp);
        fattn2<<<dim3(1024), 256, 0, stream>>>(q, kbp, vbp, vlen, out);
    } else {
        fattn_fb<<<dim3(1024), 256, 0, stream>>>(q, k, v, vlen, out);
    }
}